// Round 15
// baseline (2846.970 us; speedup 1.0000x reference)
//
#include <hip/hip_runtime.h>
#include <stdint.h>

typedef unsigned short u16;
typedef unsigned long long u64;
typedef __attribute__((ext_vector_type(8))) short bf16x8;
typedef __attribute__((ext_vector_type(4))) float f32x4;
typedef __attribute__((ext_vector_type(16))) float f32x16;
typedef __attribute__((ext_vector_type(4))) unsigned int u32x4;
typedef __attribute__((ext_vector_type(4))) unsigned short u16x4;

#define DEV static __device__ __forceinline__

DEV u16 f2bf(float f){
  unsigned u = __builtin_bit_cast(unsigned, f);
  u += 0x7fffu + ((u >> 16) & 1u);
  return (u16)(u >> 16);
}
DEV float bf2f(u16 v){
  unsigned u = ((unsigned)v) << 16;
  return __builtin_bit_cast(float, u);
}

DEV void async_lds16(const void* g, void* l){
  __builtin_amdgcn_global_load_lds(
      (const __attribute__((address_space(1))) unsigned int*)g,
      (__attribute__((address_space(3))) unsigned int*)l, 16, 0, 0);
}

DEV f32x4 mfma16(bf16x8 a, bf16x8 b, f32x4 c){
  return __builtin_amdgcn_mfma_f32_16x16x32_bf16(a, b, c, 0, 0, 0);
}
DEV f32x16 mfma32(bf16x8 a, bf16x8 b, f32x16 c){
  return __builtin_amdgcn_mfma_f32_32x32x16_bf16(a, b, c, 0, 0, 0);
}

// ---------------- RMSNorm: x (f32) -> xn (bf16), one wave per row ----------
__global__ __launch_bounds__(256) void k_rms(const float* __restrict__ x,
                                             const float* __restrict__ g,
                                             u16* __restrict__ xn){
  const int row = (blockIdx.x << 2) + (threadIdx.x >> 6);
  const int l = threadIdx.x & 63;
  const float* xr = x + (size_t)row * 512 + l * 8;
  f32x4 a = *(const f32x4*)xr;
  f32x4 c = *(const f32x4*)(xr + 4);
  float s = a[0]*a[0]+a[1]*a[1]+a[2]*a[2]+a[3]*a[3]
          + c[0]*c[0]+c[1]*c[1]+c[2]*c[2]+c[3]*c[3];
  #pragma unroll
  for (int off = 32; off >= 1; off >>= 1) s += __shfl_xor(s, off);
  float sc = rsqrtf(s * (1.f/512.f) + 1e-6f);
  f32x4 g0 = *(const f32x4*)&g[l*8];
  f32x4 g1 = *(const f32x4*)&g[l*8+4];
  u32x4 o;
  o[0] = (unsigned)f2bf(a[0]*sc*g0[0]) | ((unsigned)f2bf(a[1]*sc*g0[1]) << 16);
  o[1] = (unsigned)f2bf(a[2]*sc*g0[2]) | ((unsigned)f2bf(a[3]*sc*g0[3]) << 16);
  o[2] = (unsigned)f2bf(c[0]*sc*g1[0]) | ((unsigned)f2bf(c[1]*sc*g1[1]) << 16);
  o[3] = (unsigned)f2bf(c[2]*sc*g1[2]) | ((unsigned)f2bf(c[3]*sc*g1[3]) << 16);
  *(u32x4*)&xn[(size_t)row*512 + l*8] = o;
}

// ---- fused row L2-normalize + batched transpose:
// xright bf16 [16384][512] -> xrn bf16 (normalized) + xrT bf16 [4][512][4096]
__global__ __launch_bounds__(256) void k_ntr(const u16* __restrict__ xr_in,
                                             u16* __restrict__ xrn,
                                             u16* __restrict__ xrT){
  __shared__ u16 lds[512*36 + 16];
  const int t = threadIdx.x;
  const int r = t >> 3;
  const int c0 = (t & 7) << 6;
  const int gn = blockIdx.x << 5;
  const int b  = gn >> 12;
  const int nb = gn & 4095;
  const u16* src = xr_in + (size_t)(gn + r)*512 + c0;
  u16 v[64];
  float s = 0.f;
  #pragma unroll
  for (int k = 0; k < 16; ++k){
    u16x4 a = *(const u16x4*)(src + k*4);
    #pragma unroll
    for (int e = 0; e < 4; ++e){
      v[k*4+e] = a[e];
      float f = bf2f(a[e]);
      s += f*f;
    }
  }
  s += __shfl_xor(s, 1); s += __shfl_xor(s, 2); s += __shfl_xor(s, 4);
  float sc = 1.f / fmaxf(sqrtf(s), 1e-12f);
  u16* dst = xrn + (size_t)(gn + r)*512 + c0;
  #pragma unroll
  for (int k = 0; k < 16; ++k){
    u16x4 o;
    #pragma unroll
    for (int e = 0; e < 4; ++e){
      int c = c0 + k*4 + e;
      u16 nv = f2bf(bf2f(v[k*4+e])*sc);
      o[e] = nv;
      lds[(c*36 + r) ^ (((c >> 6) & 3) << 2)] = nv;
    }
    *(u16x4*)(dst + k*4) = o;
  }
  __syncthreads();
  u16* od = xrT + (size_t)b*(512*4096) + nb;
  #pragma unroll
  for (int e = 0; e < 2; ++e){
    int d = t*2 + e;
    const int key = ((d >> 6) & 3) << 2;
    u16 tmp[32];
    #pragma unroll
    for (int q = 0; q < 8; ++q)
      *(u16x4*)&tmp[q*4] = *(const u16x4*)&lds[(d*36 + q*4) ^ key];
    #pragma unroll
    for (int q = 0; q < 8; ++q)
      *(u64*)(od + (size_t)d*4096 + q*4) = *(const u64*)&tmp[q*4];
  }
}

// -------- transpose+cast: in f32 [R][C] -> out bf16 [C][R], 32x32 tiles -----
__global__ __launch_bounds__(256) void k_tr32(const float* __restrict__ in,
                                              u16* __restrict__ out, int R, int C){
  __shared__ float tile[32][33];
  const int t = threadIdx.x;
  const int r = t >> 3;
  const int c4 = (t & 7) << 2;
  const int r0 = blockIdx.y << 5, c0 = blockIdx.x << 5;
  f32x4 v = *(const f32x4*)&in[(size_t)(r0 + r) * C + c0 + c4];
  tile[r][c4+0]=v[0]; tile[r][c4+1]=v[1]; tile[r][c4+2]=v[2]; tile[r][c4+3]=v[3];
  __syncthreads();
  u64 o =
      (u64)f2bf(tile[c4+0][r])
    | ((u64)f2bf(tile[c4+1][r]) << 16)
    | ((u64)f2bf(tile[c4+2][r]) << 32)
    | ((u64)f2bf(tile[c4+3][r]) << 48);
  *(u64*)&out[(size_t)(c0 + r) * R + r0 + c4] = o;
}

// -------- GEMM1 (2-phase dbuf): [16384x512]x[512x2048]+b1, relu^2, split ----
__global__ __launch_bounds__(256) void k_gemm1(const u16* __restrict__ A,
                                               const u16* __restrict__ Bt,
                                               const float* __restrict__ b1,
                                               u16* __restrict__ head,
                                               u16* __restrict__ xleft,
                                               u16* __restrict__ xright){
  __shared__ u16 As[2][128*32];
  __shared__ u16 Bs[2][128*32];
  const int t = threadIdx.x;
  const int l = t & 63;
  const int w = t >> 6;
  const int wr = w >> 1, wc = w & 1;
  const int m0 = blockIdx.x << 7;
  const int n0 = blockIdx.y << 7;
  const int ra = t >> 2;
  const int kb = (t & 3) << 3;
  const int lr = l & 15, lh = l >> 4;
  f32x4 acc[4][4];
  #pragma unroll
  for (int i=0;i<4;i++)
    #pragma unroll
    for (int j=0;j<4;j++)
      #pragma unroll
      for (int r=0;r<4;r++) acc[i][j][r] = 0.f;

  async_lds16(A  + (size_t)(m0 + ra)*512      + kb, &As[0][t*8]);
  async_lds16(A  + (size_t)(m0 + 64 + ra)*512 + kb, &As[0][2048 + t*8]);
  async_lds16(Bt + (size_t)(n0 + ra)*512      + kb, &Bs[0][t*8]);
  async_lds16(Bt + (size_t)(n0 + 64 + ra)*512 + kb, &Bs[0][2048 + t*8]);
  __syncthreads();

  int cur = 0;
  for (int k0 = 0; k0 < 512; k0 += 32){
    if (k0 + 32 < 512){
      const int kn = k0 + 32;
      const int nb = cur ^ 1;
      async_lds16(A  + (size_t)(m0 + ra)*512      + kn + kb, &As[nb][t*8]);
      async_lds16(A  + (size_t)(m0 + 64 + ra)*512 + kn + kb, &As[nb][2048 + t*8]);
      async_lds16(Bt + (size_t)(n0 + ra)*512      + kn + kb, &Bs[nb][t*8]);
      async_lds16(Bt + (size_t)(n0 + 64 + ra)*512 + kn + kb, &Bs[nb][2048 + t*8]);
    }
    bf16x8 af[4], bfr[4];
    #pragma unroll
    for (int i=0;i<4;i++){
      af[i]  = *(const bf16x8*)&As[cur][(wr*64 + i*16 + lr)*32 + lh*8];
      bfr[i] = *(const bf16x8*)&Bs[cur][(wc*64 + i*16 + lr)*32 + lh*8];
    }
    #pragma unroll
    for (int i=0;i<4;i++)
      #pragma unroll
      for (int j=0;j<4;j++)
        acc[i][j] = mfma16(af[i], bfr[j], acc[i][j]);
    __syncthreads();
    cur ^= 1;
  }
  #pragma unroll
  for (int i=0;i<4;i++){
    #pragma unroll
    for (int j=0;j<4;j++){
      int c = n0 + wc*64 + j*16 + lr;
      float bb = b1[c];
      #pragma unroll
      for (int r=0;r<4;r++){
        int m = m0 + wr*64 + i*16 + lh*4 + r;
        float v = acc[i][j][r] + bb;
        v = v > 0.f ? v*v : 0.f;
        if (c < 1024)      head[(size_t)m*1024 + c] = f2bf(v);
        else if (c < 1536) xleft[(size_t)m*512 + (c - 1024)] = f2bf(v);
        else               xright[(size_t)m*512 + (c - 1536)] = f2bf(v);
      }
    }
  }
}

// -------- GEMM3 (2-phase dbuf): [head|gated](16384x1536) x Wft^T, +x --------
__global__ __launch_bounds__(256) void k_gemm3(const u16* __restrict__ head,
                                               const u16* __restrict__ gated,
                                               const u16* __restrict__ Wft,
                                               const float* __restrict__ x,
                                               float* __restrict__ out){
  __shared__ u16 As[2][128*32];
  __shared__ u16 Bs[2][128*32];
  const int t = threadIdx.x;
  const int l = t & 63;
  const int w = t >> 6;
  const int wr = w >> 1, wc = w & 1;
  const int m0 = blockIdx.x << 7;
  const int n0 = blockIdx.y << 7;
  const int ra = t >> 2;
  const int kb = (t & 3) << 3;
  const int lr = l & 15, lh = l >> 4;
  f32x4 acc[4][4];
  #pragma unroll
  for (int i=0;i<4;i++)
    #pragma unroll
    for (int j=0;j<4;j++)
      #pragma unroll
      for (int r=0;r<4;r++) acc[i][j][r] = 0.f;

  auto stage = [&](int nb, int k0){
    const u16* sa; size_t lda; int kk;
    if (k0 < 1024){ sa = head;  lda = 1024; kk = k0; }
    else          { sa = gated; lda = 512;  kk = k0 - 1024; }
    async_lds16(sa + (size_t)(m0 + ra)*lda      + kk + kb, &As[nb][t*8]);
    async_lds16(sa + (size_t)(m0 + 64 + ra)*lda + kk + kb, &As[nb][2048 + t*8]);
    async_lds16(Wft + (size_t)(n0 + ra)*1536      + k0 + kb, &Bs[nb][t*8]);
    async_lds16(Wft + (size_t)(n0 + 64 + ra)*1536 + k0 + kb, &Bs[nb][2048 + t*8]);
  };
  stage(0, 0);
  __syncthreads();

  int cur = 0;
  for (int k0 = 0; k0 < 1536; k0 += 32){
    if (k0 + 32 < 1536) stage(cur ^ 1, k0 + 32);
    bf16x8 af[4], bfr[4];
    #pragma unroll
    for (int i=0;i<4;i++){
      af[i]  = *(const bf16x8*)&As[cur][(wr*64 + i*16 + lr)*32 + lh*8];
      bfr[i] = *(const bf16x8*)&Bs[cur][(wc*64 + i*16 + lr)*32 + lh*8];
    }
    #pragma unroll
    for (int i=0;i<4;i++)
      #pragma unroll
      for (int j=0;j<4;j++)
        acc[i][j] = mfma16(af[i], bfr[j], acc[i][j]);
    __syncthreads();
    cur ^= 1;
  }
  #pragma unroll
  for (int i=0;i<4;i++){
    #pragma unroll
    for (int j=0;j<4;j++){
      int c = n0 + wc*64 + j*16 + lr;
      #pragma unroll
      for (int r=0;r<4;r++){
        int m = m0 + wr*64 + i*16 + lh*4 + r;
        size_t gi = (size_t)m*512 + c;
        out[gi] = x[gi] + acc[i][j][r];
      }
    }
  }
}

// -------- fused cos/weight/ctx/sigmoid/gate ("attention"), v12 --------------
// 2-blocks/CU diet: LDS exactly 80 KiB (km 32K single-buf, tt 32K single-buf,
// ps 16K swizzled pitch-64; pb overlays km). Same 3-phase lockstep structure;
// the co-resident block hides the per-iter stage drain (m114 overlap).
__global__ __launch_bounds__(512, 4) void k_attn(const u16* __restrict__ xrn,
                                                 const u16* __restrict__ xrT,
                                                 const float* __restrict__ V,
                                                 const float* __restrict__ bias,
                                                 const u16* __restrict__ xleft,
                                                 u16* __restrict__ gated){
  __shared__ char smem[81920];
  char* km = smem;              // [32][1024B] u16, swz byte^((row&7)<<4)
  char* tt = smem + 32768;      // [512][64B] u16,  swz byte^((dr&6)<<3)
  char* ps = smem + 65536;      // [8 sec][32 col][64B] u16^T, slot^((col&7)<<3)
  char* pb = smem;              // [64][80B] u16 (P = V*cos), overlays km
  const int t = threadIdx.x;
  const int l = t & 63, w = t >> 6;
  const int wr = w >> 2, ks = w & 3, wc = (w >> 1) & 1, kq2 = w & 1;
  const int lo = l & 31, hi = l >> 5;
  const int bid = blockIdx.x;
  const int b  = (bid & 7) >> 1;                       // XCD-pair per batch
  const int n0 = ((((bid >> 3) << 1) | (bid & 1))) << 6;
  const u16* xb  = xrn + (size_t)b * (4096*512);
  const u16* xTb = xrT + (size_t)b * (512*4096);

  // A fragments: 32 n-rows (this wr), K-quarter ks -> 8 frags (32 VGPR)
  bf16x8 areg[8];
  {
    const u16* apt = xb + (size_t)(n0 + wr*32 + lo)*512 + ks*128 + hi*8;
    #pragma unroll
    for (int kq = 0; kq < 8; ++kq) areg[kq] = *(const bf16x8*)(apt + kq*16);
  }
  f32x16 acc[8];
  #pragma unroll
  for (int i = 0; i < 8; ++i)
    #pragma unroll
    for (int j = 0; j < 16; ++j) acc[i][j] = 0.f;

  // combine mapping: thread -> (m-col 0..31, n-row-quad 0..15)
  const int ccol = t & 31;
  const int crq  = t >> 5;
  const int cwr  = crq >> 3;               // wr half of the rows
  const int cslot = (crq & 7) << 3;        // row-byte slot in ps row
  const int cgr  = crq << 2;               // global row base (0..60)

  for (int it = 0; it < 128; ++it){
    const int m0 = it << 5;
    // V prefetch (4 coalesced row-loads; consumed in combine)
    f32x4 vf;
    {
      const float* vp = V + (size_t)(n0 + cgr)*4096 + m0 + ccol;
      vf[0] = vp[0];
      vf[1] = vp[4096];
      vf[2] = vp[2*4096];
      vf[3] = vp[3*4096];
    }
    // stage THIS iter's m-tile (km + tt); pb/tt from prev iter already consumed
    #pragma unroll
    for (int c = 0; c < 2; ++c){
      int off = (c*512 + t)*16;
      int row = off >> 10, colb = off & 1023;
      async_lds16(xb + (size_t)(m0 + row)*512 + ((colb ^ ((row&7)<<4)) >> 1),
                  km + off);
      int dr = off >> 6, cb2 = off & 63;
      async_lds16(xTb + (size_t)dr*4096 + m0 + ((cb2 ^ ((dr&6)<<3)) >> 1),
                  tt + off);
      int off2 = off + 16384;
      int row2 = off2 >> 10, colb2 = off2 & 1023;
      async_lds16(xb + (size_t)(m0 + row2)*512 + ((colb2 ^ ((row2&7)<<4)) >> 1),
                  km + off2);
      int dr2 = off2 >> 6, cb22 = off2 & 63;
      async_lds16(xTb + (size_t)dr2*4096 + m0 + ((cb22 ^ ((dr2&6)<<3)) >> 1),
                  tt + off2);
    }
    __syncthreads();                       // drains staging (vmcnt 0)

    // ---- S-phase: partial S[32n(wr)][32m] over K-quarter ks ----
    f32x16 S0, S1;
    #pragma unroll
    for (int j = 0; j < 16; ++j){ S0[j] = 0.f; S1[j] = 0.f; }
    {
      const char* kbp = km + lo*1024;
      const int swk = (lo & 7) << 4;
      #pragma unroll
      for (int kq = 0; kq < 8; kq += 2){
        bf16x8 b0 = *(const bf16x8*)(kbp + ((ks*256 + kq*32 + hi*16) ^ swk));
        bf16x8 b1 = *(const bf16x8*)(kbp + ((ks*256 + (kq+1)*32 + hi*16) ^ swk));
        S0 = mfma32(areg[kq],   b0, S0);
        S1 = mfma32(areg[kq+1], b1, S1);
      }
    }
    // ps write (transposed, pitch 64, slot-swizzled)
    {
      char* pw = ps + ((wr*4 + ks)*32 + lo)*64;
      const int swp = (lo & 7) << 3;
      #pragma unroll
      for (int q = 0; q < 4; ++q){
        u64 pk = (u64)f2bf(S0[4*q+0] + S1[4*q+0])
               | ((u64)f2bf(S0[4*q+1] + S1[4*q+1]) << 16)
               | ((u64)f2bf(S0[4*q+2] + S1[4*q+2]) << 32)
               | ((u64)f2bf(S0[4*q+3] + S1[4*q+3]) << 48);
        *(u64*)(pw + ((hi*8 + q*16) ^ swp)) = pk;
      }
    }
    asm volatile("s_waitcnt lgkmcnt(0)" ::: "memory");
    __builtin_amdgcn_s_barrier();
    __builtin_amdgcn_sched_barrier(0);
    // ---- P-combine: P = (sum of 4 partials) * V -> pb (over km) ----
    {
      const char* pr0 = ps + ((cwr*4)*32 + ccol)*64 + (cslot ^ ((ccol&7)<<3));
      u16x4 q0 = *(const u16x4*)(pr0 + 0*2048);
      u16x4 q1 = *(const u16x4*)(pr0 + 1*2048);
      u16x4 q2 = *(const u16x4*)(pr0 + 2*2048);
      u16x4 q3 = *(const u16x4*)(pr0 + 3*2048);
      #pragma unroll
      for (int e = 0; e < 4; ++e){
        float s = bf2f(q0[e]) + bf2f(q1[e]) + bf2f(q2[e]) + bf2f(q3[e]);
        *(u16*)(pb + (cgr + e)*80 + ccol*2) = f2bf(s * vf[e]);
      }
    }
    asm volatile("s_waitcnt lgkmcnt(0)" ::: "memory");
    __builtin_amdgcn_s_barrier();
    __builtin_amdgcn_sched_barrier(0);
    // ---- PV: acc[32n(wr)][256d(wc)] += P[., m-half kq2] . Xr_m ----
    {
      bf16x8 pa = *(const bf16x8*)(pb + (wr*32 + lo)*80 + kq2*32 + hi*16);
      #pragma unroll
      for (int ds = 0; ds < 8; ++ds){
        int drow = wc*256 + ds*32 + lo;
        bf16x8 bfr = *(const bf16x8*)(tt + drow*64 +
                       ((kq2*32 + hi*16) ^ ((drow & 6) << 3)));
        acc[ds] = mfma32(pa, bfr, acc[ds]);
      }
    }
    __syncthreads();    // all pb/tt reads done before next iter's staging
  }

  // ---- epilogue: two-round cross-kq2 reduce (fits 64 KiB), static indices --
  float* red = (float*)smem;
  const int gbase = (wr*2 + wc) * 4096;
  // round 1: kq2==1 exports acc[0..3]; kq2==0 gates+stores ds 0..3
  if (kq2 == 1){
    #pragma unroll
    for (int ds = 0; ds < 4; ++ds)
      #pragma unroll
      for (int rg = 0; rg < 16; ++rg)
        red[gbase + (ds*16 + rg)*64 + l] = acc[ds][rg];
  }
  __syncthreads();
  if (kq2 == 0){
    #pragma unroll
    for (int ds = 0; ds < 4; ++ds){
      const int d = wc*256 + ds*32 + lo;
      const float bs = bias[d];
      #pragma unroll
      for (int rg = 0; rg < 16; ++rg){
        int row = n0 + wr*32 + (rg & 3) + 8*(rg >> 2) + 4*hi;
        float v = acc[ds][rg] + red[gbase + (ds*16 + rg)*64 + l] + bs;
        v = 1.f / (1.f + __expf(-v));
        size_t gi = (size_t)(b*4096 + row)*512 + d;
        gated[gi] = f2bf(bf2f(xleft[gi]) * v);
      }
    }
  }
  __syncthreads();
  // round 2: kq2==0 exports acc[4..7]; kq2==1 gates+stores ds 4..7
  if (kq2 == 0){
    #pragma unroll
    for (int ds = 0; ds < 4; ++ds)
      #pragma unroll
      for (int rg = 0; rg < 16; ++rg)
        red[gbase + (ds*16 + rg)*64 + l] = acc[4 + ds][rg];
  }
  __syncthreads();
  if (kq2 == 1){
    #pragma unroll
    for (int ds = 0; ds < 4; ++ds){
      const int d = wc*256 + (4 + ds)*32 + lo;
      const float bs = bias[d];
      #pragma unroll
      for (int rg = 0; rg < 16; ++rg){
        int row = n0 + wr*32 + (rg & 3) + 8*(rg >> 2) + 4*hi;
        float v = acc[4 + ds][rg] + red[gbase + (ds*16 + rg)*64 + l] + bs;
        v = 1.f / (1.f + __expf(-v));
        size_t gi = (size_t)(b*4096 + row)*512 + d;
        gated[gi] = f2bf(bf2f(xleft[gi]) * v);
      }
    }
  }
}

extern "C" void kernel_launch(void* const* d_in, const int* in_sizes, int n_in,
                              void* d_out, int out_size, void* d_ws, size_t ws_size,
                              hipStream_t stream){
  const float* x    = (const float*)d_in[0];
  const float* g    = (const float*)d_in[1];
  const float* W1   = (const float*)d_in[2];
  const float* b1   = (const float*)d_in[3];
  const float* V    = (const float*)d_in[4];
  const float* bias = (const float*)d_in[5];
  const float* Wf   = (const float*)d_in[6];
  float* out = (float*)d_out;

  char* ws = (char*)d_ws;
  const size_t MB = 1024u*1024u;
  u16*   xn     = (u16*)  (ws + 0*MB);     // 16 MiB
  u16*   W1t    = (u16*)  (ws + 16*MB);    //  2 MiB
  u16*   Wft    = (u16*)  (ws + 18*MB);    //  1.5 MiB
  u16*   head   = (u16*)  (ws + 20*MB);    // 32 MiB
  u16*   xleft  = (u16*)  (ws + 52*MB);    // 16 MiB (bf16)
  u16*   xright = (u16*)  (ws + 68*MB);    // 16 MiB (bf16) [dead after k_ntr]
  u16*   gated  = (u16*)  (ws + 68*MB);    // 16 MiB (overlays xright)
  u16*   xrn    = (u16*)  (ws + 84*MB);    // 16 MiB
  u16*   xrT    = (u16*)  (ws + 100*MB);   // 16 MiB

  k_rms  <<<dim3(4096),    dim3(256), 0, stream>>>(x, g, xn);
  k_tr32 <<<dim3(64, 16),  dim3(256), 0, stream>>>(W1, W1t, 512, 2048);
  k_tr32 <<<dim3(16, 48),  dim3(256), 0, stream>>>(Wf, Wft, 1536, 512);
  k_gemm1<<<dim3(128, 16), dim3(256), 0, stream>>>(xn, W1t, b1, head, xleft, xright);
  k_ntr  <<<dim3(512),     dim3(256), 0, stream>>>(xright, xrn, xrT);
  k_attn <<<dim3(256),     dim3(512), 0, stream>>>(xrn, xrT, V, bias, xleft, gated);
  k_gemm3<<<dim3(128, 4),  dim3(256), 0, stream>>>(head, gated, Wft, x, out);
}

// Round 16
// 365.113 us; speedup vs baseline: 7.7975x; 7.7975x over previous
//
#include <hip/hip_runtime.h>
#include <stdint.h>

typedef unsigned short u16;
typedef unsigned long long u64;
typedef __attribute__((ext_vector_type(8))) short bf16x8;
typedef __attribute__((ext_vector_type(4))) float f32x4;
typedef __attribute__((ext_vector_type(16))) float f32x16;
typedef __attribute__((ext_vector_type(4))) unsigned int u32x4;
typedef __attribute__((ext_vector_type(4))) unsigned short u16x4;

#define DEV static __device__ __forceinline__

DEV u16 f2bf(float f){
  unsigned u = __builtin_bit_cast(unsigned, f);
  u += 0x7fffu + ((u >> 16) & 1u);
  return (u16)(u >> 16);
}
DEV float bf2f(u16 v){
  unsigned u = ((unsigned)v) << 16;
  return __builtin_bit_cast(float, u);
}

DEV void async_lds16(const void* g, void* l){
  __builtin_amdgcn_global_load_lds(
      (const __attribute__((address_space(1))) unsigned int*)g,
      (__attribute__((address_space(3))) unsigned int*)l, 16, 0, 0);
}

DEV f32x4 mfma16(bf16x8 a, bf16x8 b, f32x4 c){
  return __builtin_amdgcn_mfma_f32_16x16x32_bf16(a, b, c, 0, 0, 0);
}
DEV f32x16 mfma32(bf16x8 a, bf16x8 b, f32x16 c){
  return __builtin_amdgcn_mfma_f32_32x32x16_bf16(a, b, c, 0, 0, 0);
}

// ---------------- RMSNorm: x (f32) -> xn (bf16), one wave per row ----------
__global__ __launch_bounds__(256) void k_rms(const float* __restrict__ x,
                                             const float* __restrict__ g,
                                             u16* __restrict__ xn){
  const int row = (blockIdx.x << 2) + (threadIdx.x >> 6);
  const int l = threadIdx.x & 63;
  const float* xr = x + (size_t)row * 512 + l * 8;
  f32x4 a = *(const f32x4*)xr;
  f32x4 c = *(const f32x4*)(xr + 4);
  float s = a[0]*a[0]+a[1]*a[1]+a[2]*a[2]+a[3]*a[3]
          + c[0]*c[0]+c[1]*c[1]+c[2]*c[2]+c[3]*c[3];
  #pragma unroll
  for (int off = 32; off >= 1; off >>= 1) s += __shfl_xor(s, off);
  float sc = rsqrtf(s * (1.f/512.f) + 1e-6f);
  f32x4 g0 = *(const f32x4*)&g[l*8];
  f32x4 g1 = *(const f32x4*)&g[l*8+4];
  u32x4 o;
  o[0] = (unsigned)f2bf(a[0]*sc*g0[0]) | ((unsigned)f2bf(a[1]*sc*g0[1]) << 16);
  o[1] = (unsigned)f2bf(a[2]*sc*g0[2]) | ((unsigned)f2bf(a[3]*sc*g0[3]) << 16);
  o[2] = (unsigned)f2bf(c[0]*sc*g1[0]) | ((unsigned)f2bf(c[1]*sc*g1[1]) << 16);
  o[3] = (unsigned)f2bf(c[2]*sc*g1[2]) | ((unsigned)f2bf(c[3]*sc*g1[3]) << 16);
  *(u32x4*)&xn[(size_t)row*512 + l*8] = o;
}

// ---- fused row L2-normalize + batched transpose:
// xright bf16 [16384][512] -> xrn bf16 (normalized) + xrT bf16 [4][512][4096]
__global__ __launch_bounds__(256) void k_ntr(const u16* __restrict__ xr_in,
                                             u16* __restrict__ xrn,
                                             u16* __restrict__ xrT){
  __shared__ u16 lds[512*36 + 16];
  const int t = threadIdx.x;
  const int r = t >> 3;
  const int c0 = (t & 7) << 6;
  const int gn = blockIdx.x << 5;
  const int b  = gn >> 12;
  const int nb = gn & 4095;
  const u16* src = xr_in + (size_t)(gn + r)*512 + c0;
  u16 v[64];
  float s = 0.f;
  #pragma unroll
  for (int k = 0; k < 16; ++k){
    u16x4 a = *(const u16x4*)(src + k*4);
    #pragma unroll
    for (int e = 0; e < 4; ++e){
      v[k*4+e] = a[e];
      float f = bf2f(a[e]);
      s += f*f;
    }
  }
  s += __shfl_xor(s, 1); s += __shfl_xor(s, 2); s += __shfl_xor(s, 4);
  float sc = 1.f / fmaxf(sqrtf(s), 1e-12f);
  u16* dst = xrn + (size_t)(gn + r)*512 + c0;
  #pragma unroll
  for (int k = 0; k < 16; ++k){
    u16x4 o;
    #pragma unroll
    for (int e = 0; e < 4; ++e){
      int c = c0 + k*4 + e;
      u16 nv = f2bf(bf2f(v[k*4+e])*sc);
      o[e] = nv;
      lds[(c*36 + r) ^ (((c >> 6) & 3) << 2)] = nv;
    }
    *(u16x4*)(dst + k*4) = o;
  }
  __syncthreads();
  u16* od = xrT + (size_t)b*(512*4096) + nb;
  #pragma unroll
  for (int e = 0; e < 2; ++e){
    int d = t*2 + e;
    const int key = ((d >> 6) & 3) << 2;
    u16 tmp[32];
    #pragma unroll
    for (int q = 0; q < 8; ++q)
      *(u16x4*)&tmp[q*4] = *(const u16x4*)&lds[(d*36 + q*4) ^ key];
    #pragma unroll
    for (int q = 0; q < 8; ++q)
      *(u64*)(od + (size_t)d*4096 + q*4) = *(const u64*)&tmp[q*4];
  }
}

// -------- transpose+cast: in f32 [R][C] -> out bf16 [C][R], 32x32 tiles -----
__global__ __launch_bounds__(256) void k_tr32(const float* __restrict__ in,
                                              u16* __restrict__ out, int R, int C){
  __shared__ float tile[32][33];
  const int t = threadIdx.x;
  const int r = t >> 3;
  const int c4 = (t & 7) << 2;
  const int r0 = blockIdx.y << 5, c0 = blockIdx.x << 5;
  f32x4 v = *(const f32x4*)&in[(size_t)(r0 + r) * C + c0 + c4];
  tile[r][c4+0]=v[0]; tile[r][c4+1]=v[1]; tile[r][c4+2]=v[2]; tile[r][c4+3]=v[3];
  __syncthreads();
  u64 o =
      (u64)f2bf(tile[c4+0][r])
    | ((u64)f2bf(tile[c4+1][r]) << 16)
    | ((u64)f2bf(tile[c4+2][r]) << 32)
    | ((u64)f2bf(tile[c4+3][r]) << 48);
  *(u64*)&out[(size_t)(c0 + r) * R + r0 + c4] = o;
}

// -------- GEMM1 (2-phase dbuf): [16384x512]x[512x2048]+b1, relu^2, split ----
__global__ __launch_bounds__(256) void k_gemm1(const u16* __restrict__ A,
                                               const u16* __restrict__ Bt,
                                               const float* __restrict__ b1,
                                               u16* __restrict__ head,
                                               u16* __restrict__ xleft,
                                               u16* __restrict__ xright){
  __shared__ u16 As[2][128*32];
  __shared__ u16 Bs[2][128*32];
  const int t = threadIdx.x;
  const int l = t & 63;
  const int w = t >> 6;
  const int wr = w >> 1, wc = w & 1;
  const int m0 = blockIdx.x << 7;
  const int n0 = blockIdx.y << 7;
  const int ra = t >> 2;
  const int kb = (t & 3) << 3;
  const int lr = l & 15, lh = l >> 4;
  f32x4 acc[4][4];
  #pragma unroll
  for (int i=0;i<4;i++)
    #pragma unroll
    for (int j=0;j<4;j++)
      #pragma unroll
      for (int r=0;r<4;r++) acc[i][j][r] = 0.f;

  async_lds16(A  + (size_t)(m0 + ra)*512      + kb, &As[0][t*8]);
  async_lds16(A  + (size_t)(m0 + 64 + ra)*512 + kb, &As[0][2048 + t*8]);
  async_lds16(Bt + (size_t)(n0 + ra)*512      + kb, &Bs[0][t*8]);
  async_lds16(Bt + (size_t)(n0 + 64 + ra)*512 + kb, &Bs[0][2048 + t*8]);
  __syncthreads();

  int cur = 0;
  for (int k0 = 0; k0 < 512; k0 += 32){
    if (k0 + 32 < 512){
      const int kn = k0 + 32;
      const int nb = cur ^ 1;
      async_lds16(A  + (size_t)(m0 + ra)*512      + kn + kb, &As[nb][t*8]);
      async_lds16(A  + (size_t)(m0 + 64 + ra)*512 + kn + kb, &As[nb][2048 + t*8]);
      async_lds16(Bt + (size_t)(n0 + ra)*512      + kn + kb, &Bs[nb][t*8]);
      async_lds16(Bt + (size_t)(n0 + 64 + ra)*512 + kn + kb, &Bs[nb][2048 + t*8]);
    }
    bf16x8 af[4], bfr[4];
    #pragma unroll
    for (int i=0;i<4;i++){
      af[i]  = *(const bf16x8*)&As[cur][(wr*64 + i*16 + lr)*32 + lh*8];
      bfr[i] = *(const bf16x8*)&Bs[cur][(wc*64 + i*16 + lr)*32 + lh*8];
    }
    #pragma unroll
    for (int i=0;i<4;i++)
      #pragma unroll
      for (int j=0;j<4;j++)
        acc[i][j] = mfma16(af[i], bfr[j], acc[i][j]);
    __syncthreads();
    cur ^= 1;
  }
  #pragma unroll
  for (int i=0;i<4;i++){
    #pragma unroll
    for (int j=0;j<4;j++){
      int c = n0 + wc*64 + j*16 + lr;
      float bb = b1[c];
      #pragma unroll
      for (int r=0;r<4;r++){
        int m = m0 + wr*64 + i*16 + lh*4 + r;
        float v = acc[i][j][r] + bb;
        v = v > 0.f ? v*v : 0.f;
        if (c < 1024)      head[(size_t)m*1024 + c] = f2bf(v);
        else if (c < 1536) xleft[(size_t)m*512 + (c - 1024)] = f2bf(v);
        else               xright[(size_t)m*512 + (c - 1536)] = f2bf(v);
      }
    }
  }
}

// -------- GEMM3 (2-phase dbuf): [head|gated](16384x1536) x Wft^T, +x --------
__global__ __launch_bounds__(256) void k_gemm3(const u16* __restrict__ head,
                                               const u16* __restrict__ gated,
                                               const u16* __restrict__ Wft,
                                               const float* __restrict__ x,
                                               float* __restrict__ out){
  __shared__ u16 As[2][128*32];
  __shared__ u16 Bs[2][128*32];
  const int t = threadIdx.x;
  const int l = t & 63;
  const int w = t >> 6;
  const int wr = w >> 1, wc = w & 1;
  const int m0 = blockIdx.x << 7;
  const int n0 = blockIdx.y << 7;
  const int ra = t >> 2;
  const int kb = (t & 3) << 3;
  const int lr = l & 15, lh = l >> 4;
  f32x4 acc[4][4];
  #pragma unroll
  for (int i=0;i<4;i++)
    #pragma unroll
    for (int j=0;j<4;j++)
      #pragma unroll
      for (int r=0;r<4;r++) acc[i][j][r] = 0.f;

  auto stage = [&](int nb, int k0){
    const u16* sa; size_t lda; int kk;
    if (k0 < 1024){ sa = head;  lda = 1024; kk = k0; }
    else          { sa = gated; lda = 512;  kk = k0 - 1024; }
    async_lds16(sa + (size_t)(m0 + ra)*lda      + kk + kb, &As[nb][t*8]);
    async_lds16(sa + (size_t)(m0 + 64 + ra)*lda + kk + kb, &As[nb][2048 + t*8]);
    async_lds16(Wft + (size_t)(n0 + ra)*1536      + k0 + kb, &Bs[nb][t*8]);
    async_lds16(Wft + (size_t)(n0 + 64 + ra)*1536 + k0 + kb, &Bs[nb][2048 + t*8]);
  };
  stage(0, 0);
  __syncthreads();

  int cur = 0;
  for (int k0 = 0; k0 < 1536; k0 += 32){
    if (k0 + 32 < 1536) stage(cur ^ 1, k0 + 32);
    bf16x8 af[4], bfr[4];
    #pragma unroll
    for (int i=0;i<4;i++){
      af[i]  = *(const bf16x8*)&As[cur][(wr*64 + i*16 + lr)*32 + lh*8];
      bfr[i] = *(const bf16x8*)&Bs[cur][(wc*64 + i*16 + lr)*32 + lh*8];
    }
    #pragma unroll
    for (int i=0;i<4;i++)
      #pragma unroll
      for (int j=0;j<4;j++)
        acc[i][j] = mfma16(af[i], bfr[j], acc[i][j]);
    __syncthreads();
    cur ^= 1;
  }
  #pragma unroll
  for (int i=0;i<4;i++){
    #pragma unroll
    for (int j=0;j<4;j++){
      int c = n0 + wc*64 + j*16 + lr;
      #pragma unroll
      for (int r=0;r<4;r++){
        int m = m0 + wr*64 + i*16 + lh*4 + r;
        size_t gi = (size_t)m*512 + c;
        out[gi] = x[gi] + acc[i][j][r];
      }
    }
  }
}

// -------- fused cos/weight/ctx/sigmoid/gate ("attention"), v11 --------------
// Proven r14 kernel: 8 waves, n-tile 64, m-tile 32, double-buffered staging,
// transposed ps (b64 writes), split static-index epilogue. 268-272 us stable.
__global__ __launch_bounds__(512, 2) void k_attn(const u16* __restrict__ xrn,
                                                 const u16* __restrict__ xrT,
                                                 const float* __restrict__ V,
                                                 const float* __restrict__ bias,
                                                 const u16* __restrict__ xleft,
                                                 u16* __restrict__ gated){
  __shared__ char smem[154624];
  char* km = smem;              // [2][32][1024B] u16, swz byte^((row&7)<<4)
  char* tt = smem + 65536;      // [2][512][64B] u16,  swz byte^((dr&6)<<3)
  char* ps = smem + 131072;     // [8 sec][32 col][72B rows] u16^T -> 149504
  char* pb = smem + 149504;     // [64 row][80B] u16 (P = V*cos)   -> 154624
  const int t = threadIdx.x;
  const int l = t & 63, w = t >> 6;
  const int wr = w >> 2, ks = w & 3, wc = (w >> 1) & 1, kq2 = w & 1;
  const int lo = l & 31, hi = l >> 5;
  const int bid = blockIdx.x;
  const int b  = (bid & 7) >> 1;                       // XCD-pair per batch
  const int n0 = ((((bid >> 3) << 1) | (bid & 1))) << 6;
  const u16* xb  = xrn + (size_t)b * (4096*512);
  const u16* xTb = xrT + (size_t)b * (512*4096);

  // A fragments: 32 n-rows (this wr), K-quarter ks -> 8 frags (32 VGPR)
  bf16x8 areg[8];
  {
    const u16* apt = xb + (size_t)(n0 + wr*32 + lo)*512 + ks*128 + hi*8;
    #pragma unroll
    for (int kq = 0; kq < 8; ++kq) areg[kq] = *(const bf16x8*)(apt + kq*16);
  }
  f32x16 acc[8];
  #pragma unroll
  for (int i = 0; i < 8; ++i)
    #pragma unroll
    for (int j = 0; j < 16; ++j) acc[i][j] = 0.f;

  // combine mapping: thread -> (m-col 0..31, n-row-quad 0..15)
  const int ccol = t & 31;
  const int crq  = t >> 5;
  const int cwr  = crq >> 3;               // wr half of the rows
  const int clr  = (crq & 7) << 2;         // local row base in section
  const int cgr  = crq << 2;               // global row base (0..60)

  // prologue: stage m-tile 0 into buf 0
  #pragma unroll
  for (int c = 0; c < 4; ++c){
    int off = (c*512 + t)*16;
    int row = off >> 10, colb = off & 1023;
    async_lds16(xb + (size_t)row*512 + ((colb ^ ((row&7)<<4)) >> 1), km + off);
    int dr = off >> 6, cb2 = off & 63;
    async_lds16(xTb + (size_t)dr*4096 + ((cb2 ^ ((dr&6)<<3)) >> 1), tt + off);
  }
  __syncthreads();

  int cur = 0;
  for (int it = 0; it < 128; ++it){
    const int m0 = it << 5;
    // V prefetch for this iter (4 coalesced row-loads; consumed in combine)
    f32x4 vf;
    {
      const float* vp = V + (size_t)(n0 + cgr)*4096 + m0 + ccol;
      vf[0] = vp[0];
      vf[1] = vp[4096];
      vf[2] = vp[2*4096];
      vf[3] = vp[3*4096];
    }
    // stage next m-tile into the other buffer (stays in flight all iter)
    if (it < 127){
      const int m1 = m0 + 32;
      const int nb = (cur ^ 1) * 32768;
      #pragma unroll
      for (int c = 0; c < 4; ++c){
        int off = (c*512 + t)*16;
        int row = off >> 10, colb = off & 1023;
        async_lds16(xb + (size_t)(m1 + row)*512 + ((colb ^ ((row&7)<<4)) >> 1),
                    km + nb + off);
        int dr = off >> 6, cb2 = off & 63;
        async_lds16(xTb + (size_t)dr*4096 + m1 + ((cb2 ^ ((dr&6)<<3)) >> 1),
                    tt + nb + off);
      }
    }
    // ---- S-phase: partial S[32n(wr)][32m] over K-quarter ks ----
    f32x16 S0, S1;
    #pragma unroll
    for (int j = 0; j < 16; ++j){ S0[j] = 0.f; S1[j] = 0.f; }
    {
      const char* kbp = km + cur*32768 + lo*1024;
      const int swk = (lo & 7) << 4;
      #pragma unroll
      for (int kq = 0; kq < 8; kq += 2){
        bf16x8 b0 = *(const bf16x8*)(kbp + ((ks*256 + kq*32 + hi*16) ^ swk));
        bf16x8 b1 = *(const bf16x8*)(kbp + ((ks*256 + (kq+1)*32 + hi*16) ^ swk));
        S0 = mfma32(areg[kq],   b0, S0);
        S1 = mfma32(areg[kq+1], b1, S1);
      }
    }
    // ps write (transposed): lane = col lo; 4-row quads packed as u64
    {
      char* pw = ps + ((wr*4 + ks)*32 + lo)*72 + hi*8;
      #pragma unroll
      for (int q = 0; q < 4; ++q){
        u64 pk = (u64)f2bf(S0[4*q+0] + S1[4*q+0])
               | ((u64)f2bf(S0[4*q+1] + S1[4*q+1]) << 16)
               | ((u64)f2bf(S0[4*q+2] + S1[4*q+2]) << 32)
               | ((u64)f2bf(S0[4*q+3] + S1[4*q+3]) << 48);
        *(u64*)(pw + q*16) = pk;     // rows 8q+4hi+0..3
      }
    }
    asm volatile("s_waitcnt lgkmcnt(0)" ::: "memory");
    __builtin_amdgcn_s_barrier();
    __builtin_amdgcn_sched_barrier(0);
    // ---- P-combine: P = (sum of 4 partials) * V -> pb (row-major) ----
    {
      const char* pr0 = ps + ((cwr*4)*32 + ccol)*72 + clr*2;
      u16x4 q0 = *(const u16x4*)(pr0 + 0*2304);
      u16x4 q1 = *(const u16x4*)(pr0 + 1*2304);
      u16x4 q2 = *(const u16x4*)(pr0 + 2*2304);
      u16x4 q3 = *(const u16x4*)(pr0 + 3*2304);
      #pragma unroll
      for (int e = 0; e < 4; ++e){
        float s = bf2f(q0[e]) + bf2f(q1[e]) + bf2f(q2[e]) + bf2f(q3[e]);
        *(u16*)(pb + (cgr + e)*80 + ccol*2) = f2bf(s * vf[e]);
      }
    }
    asm volatile("s_waitcnt lgkmcnt(0)" ::: "memory");
    __builtin_amdgcn_s_barrier();
    __builtin_amdgcn_sched_barrier(0);
    // ---- PV: acc[32n(wr)][256d(wc)] += P[., m-half kq2] . Xr_m ----
    {
      bf16x8 pa = *(const bf16x8*)(pb + (wr*32 + lo)*80 + kq2*32 + hi*16);
      const char* tb = tt + cur*32768;
      #pragma unroll
      for (int ds = 0; ds < 8; ++ds){
        int drow = wc*256 + ds*32 + lo;
        bf16x8 bfr = *(const bf16x8*)(tb + drow*64 +
                       ((kq2*32 + hi*16) ^ ((drow & 6) << 3)));
        acc[ds] = mfma32(pa, bfr, acc[ds]);
      }
    }
    __syncthreads();    // full drain: next tile staged, all LDS reads done
    cur ^= 1;
  }

  // ---- epilogue: split cross-kq2 reduce, STATIC acc indices in each branch --
  float* red = (float*)smem;
  const int rbase = (wr*2 + wc) * 8192;
  if (kq2 == 1){
    #pragma unroll
    for (int ds = 0; ds < 4; ++ds)
      #pragma unroll
      for (int rg = 0; rg < 16; ++rg)
        red[rbase + (ds*16 + rg)*64 + l] = acc[ds][rg];
  } else {
    #pragma unroll
    for (int ds = 0; ds < 4; ++ds)
      #pragma unroll
      for (int rg = 0; rg < 16; ++rg)
        red[rbase + ((4 + ds)*16 + rg)*64 + l] = acc[4 + ds][rg];
  }
  __syncthreads();
  if (kq2 == 1){
    #pragma unroll
    for (int ds = 0; ds < 4; ++ds){
      const int d = wc*256 + (4 + ds)*32 + lo;
      const float bs = bias[d];
      #pragma unroll
      for (int rg = 0; rg < 16; ++rg){
        int row = n0 + wr*32 + (rg & 3) + 8*(rg >> 2) + 4*hi;
        float v = acc[4 + ds][rg] + red[rbase + ((4 + ds)*16 + rg)*64 + l] + bs;
        v = 1.f / (1.f + __expf(-v));
        size_t gi = (size_t)(b*4096 + row)*512 + d;
        gated[gi] = f2bf(bf2f(xleft[gi]) * v);
      }
    }
  } else {
    #pragma unroll
    for (int ds = 0; ds < 4; ++ds){
      const int d = wc*256 + ds*32 + lo;
      const float bs = bias[d];
      #pragma unroll
      for (int rg = 0; rg < 16; ++rg){
        int row = n0 + wr*32 + (rg & 3) + 8*(rg >> 2) + 4*hi;
        float v = acc[ds][rg] + red[rbase + (ds*16 + rg)*64 + l] + bs;
        v = 1.f / (1.f + __expf(-v));
        size_t gi = (size_t)(b*4096 + row)*512 + d;
        gated[gi] = f2bf(bf2f(xleft[gi]) * v);
      }
    }
  }
}

extern "C" void kernel_launch(void* const* d_in, const int* in_sizes, int n_in,
                              void* d_out, int out_size, void* d_ws, size_t ws_size,
                              hipStream_t stream){
  const float* x    = (const float*)d_in[0];
  const float* g    = (const float*)d_in[1];
  const float* W1   = (const float*)d_in[2];
  const float* b1   = (const float*)d_in[3];
  const float* V    = (const float*)d_in[4];
  const float* bias = (const float*)d_in[5];
  const float* Wf   = (const float*)d_in[6];
  float* out = (float*)d_out;

  char* ws = (char*)d_ws;
  const size_t MB = 1024u*1024u;
  u16*   xn     = (u16*)  (ws + 0*MB);     // 16 MiB
  u16*   W1t    = (u16*)  (ws + 16*MB);    //  2 MiB
  u16*   Wft    = (u16*)  (ws + 18*MB);    //  1.5 MiB
  u16*   head   = (u16*)  (ws + 20*MB);    // 32 MiB
  u16*   xleft  = (u16*)  (ws + 52*MB);    // 16 MiB (bf16)
  u16*   xright = (u16*)  (ws + 68*MB);    // 16 MiB (bf16) [dead after k_ntr]
  u16*   gated  = (u16*)  (ws + 68*MB);    // 16 MiB (overlays xright)
  u16*   xrn    = (u16*)  (ws + 84*MB);    // 16 MiB
  u16*   xrT    = (u16*)  (ws + 100*MB);   // 16 MiB

  k_rms  <<<dim3(4096),    dim3(256), 0, stream>>>(x, g, xn);
  k_tr32 <<<dim3(64, 16),  dim3(256), 0, stream>>>(W1, W1t, 512, 2048);
  k_tr32 <<<dim3(16, 48),  dim3(256), 0, stream>>>(Wf, Wft, 1536, 512);
  k_gemm1<<<dim3(128, 16), dim3(256), 0, stream>>>(xn, W1t, b1, head, xleft, xright);
  k_ntr  <<<dim3(512),     dim3(256), 0, stream>>>(xright, xrn, xrT);
  k_attn <<<dim3(256),     dim3(512), 0, stream>>>(xrn, xrT, V, bias, xleft, gated);
  k_gemm3<<<dim3(128, 4),  dim3(256), 0, stream>>>(head, gated, Wft, x, out);
}